// Round 7
// baseline (477.299 us; speedup 1.0000x reference)
//
#include <hip/hip_runtime.h>
#include <math.h>

// ---------------------------------------------------------------------------
// GCNGuard forward: 2x (guard-weights + linear + weighted aggregation)
// Edges sorted by (row, col) [np.unique axis=0], no self loops, unique.
// Round 6 -> 7: sim computation made PER-EDGE (no per-row loop) to maximize
// memory-level parallelism; guard finalization (row_sum/deg -> invs/self_w)
// fused into agg's phase A (contiguous scan, full-wave butterfly).
// ---------------------------------------------------------------------------

// 4 nodes per wave, 16 lanes per node: inv L2 norm of 128-dim feature row.
__global__ void inv_norm_kernel(const float* __restrict__ x,
                                float* __restrict__ inv_n, int N) {
    int wave = (blockIdx.x * blockDim.x + threadIdx.x) >> 6;
    int lane = threadIdx.x & 63;
    int sub = lane >> 4, sl = lane & 15;
    int node = wave * 4 + sub;
    if (node >= N) return;
    const float4* xr = (const float4*)(x + (size_t)node * 128);
    float4 a = xr[sl];
    float4 b = xr[16 + sl];
    float s = a.x * a.x + a.y * a.y + a.z * a.z + a.w * a.w
            + b.x * b.x + b.y * b.y + b.z * b.z + b.w * b.w;
#pragma unroll
    for (int off = 1; off < 16; off <<= 1) s += __shfl_xor(s, off);
    if (sl == 0) {
        float n = sqrtf(s);
        inv_n[node] = (n == 0.f) ? 1.f : 1.f / n;
    }
}

// Build CSR row_ptr from sorted row[] (one thread per edge, boundary fill).
__global__ void row_ptr_kernel(const int* __restrict__ row,
                               int* __restrict__ row_ptr, int E, int N) {
    int e = blockIdx.x * blockDim.x + threadIdx.x;
    if (e >= E) return;
    int r = row[e];
    if (e == 0) {
        for (int i = 0; i <= r; ++i) row_ptr[i] = 0;
    } else {
        int rp = row[e - 1];
        for (int i = rp + 1; i <= r; ++i) row_ptr[i] = e;
    }
    if (e == E - 1) {
        for (int i = r + 1; i <= N; ++i) row_ptr[i] = E;
    }
}

// PER-EDGE cosine sim: 4 edges per wave, 16 lanes per edge, one shot.
// All gathers independent -> MLP limited only by resident waves x 8
// in-flight dwordx4 each. Row-feature loads are L1-hot (edges sorted by
// row). edge_w[e] = thresholded raw sim.
__global__ void sim_kernel(const float* __restrict__ feat,
                           const float* __restrict__ inv_n,
                           const int* __restrict__ row,
                           const int* __restrict__ col,
                           float* __restrict__ edge_w, int E) {
    int wid  = (blockIdx.x * blockDim.x + threadIdx.x) >> 6;
    int lane = threadIdx.x & 63;
    int sub  = lane >> 4, sl = lane & 15;
    int e = wid * 4 + sub;               // uniform across the 16-lane group
    if (e >= E) return;
    int r = row[e], c = col[e];
    const float4* fr = (const float4*)(feat + (size_t)r * 128);
    const float4* fc = (const float4*)(feat + (size_t)c * 128);
    float4 ra = fr[sl], rb = fr[16 + sl];
    float4 ca = fc[sl], cb = fc[16 + sl];
    float p = ra.x * ca.x + ra.y * ca.y + ra.z * ca.z + ra.w * ca.w
            + rb.x * cb.x + rb.y * cb.y + rb.z * cb.z + rb.w * cb.w;
#pragma unroll
    for (int off = 1; off < 16; off <<= 1) p += __shfl_xor(p, off);
    float s = p * inv_n[r] * inv_n[c];
    s = (s < 0.1f) ? 0.f : s;            // SIM_THRESH
    if (sl == 0) edge_w[e] = s;          // 4 lane0s/wave -> consecutive addrs
}

// Tiled fp32 GEMM: out[N x M] = A[N x 128] @ W[128 x M] + bias.
template <int M>
__launch_bounds__(256, 2)
__global__ void gemm_kernel(const float* __restrict__ A,
                            const float* __restrict__ W,
                            const float* __restrict__ bias,
                            float* __restrict__ out, int N) {
    __shared__ float Wl[128 * M];
    const int t = threadIdx.x;
    for (int i = t; i < 128 * M; i += 256) Wl[i] = W[i];
    __syncthreads();
    const int tr = t >> 4;
    const int tc = t & 15;
    const int i0 = blockIdx.x * 64 + tr * 4;
    const float4* Arow[4];
#pragma unroll
    for (int q = 0; q < 4; ++q) {
        int rq = i0 + q;
        rq = rq < N ? rq : (N - 1);
        Arow[q] = (const float4*)(A + (size_t)rq * 128);
    }
#pragma unroll
    for (int j0i = 0; j0i < M / 64; ++j0i) {
        const int j0 = j0i * 64 + tc * 4;
        float acc[4][4] = {};
        for (int k4 = 0; k4 < 32; ++k4) {
            float4 a[4], w[4];
#pragma unroll
            for (int q = 0; q < 4; ++q) a[q] = Arow[q][k4];
#pragma unroll
            for (int kk = 0; kk < 4; ++kk)
                w[kk] = *(const float4*)&Wl[(k4 * 4 + kk) * M + j0];
#pragma unroll
            for (int q = 0; q < 4; ++q) {
                const float av[4] = {a[q].x, a[q].y, a[q].z, a[q].w};
#pragma unroll
                for (int kk = 0; kk < 4; ++kk) {
                    const float wv[4] = {w[kk].x, w[kk].y, w[kk].z, w[kk].w};
#pragma unroll
                    for (int c = 0; c < 4; ++c) acc[q][c] += av[kk] * wv[c];
                }
            }
        }
        float4 bv = *(const float4*)&bias[j0];
#pragma unroll
        for (int q = 0; q < 4; ++q) {
            if (i0 + q < N) {
                float4 o;
                o.x = acc[q][0] + bv.x;
                o.y = acc[q][1] + bv.y;
                o.z = acc[q][2] + bv.z;
                o.w = acc[q][3] + bv.w;
                *(float4*)&out[(size_t)(i0 + q) * M + j0] = o;
            }
        }
    }
}

// One wave per row. Phase A: contiguous scan of edge_w[e0..e1] -> row_sum,
// deg -> invs, self_w in registers (guard finalize fused here). Phase B:
// depth-2 pipelined gather-accumulate; dead edges (s==0) redirect to the
// cache-hot self row with weight 0.
template <int M, bool RELU>
__global__ void agg_kernel(const float* __restrict__ h,
                           const float* __restrict__ edge_w,
                           const int* __restrict__ col,
                           const int* __restrict__ row_ptr,
                           float* __restrict__ out, int N) {
    int r    = (blockIdx.x * blockDim.x + threadIdx.x) >> 6;
    int lane = threadIdx.x & 63;
    int sub  = lane >> 4, sl = lane & 15;
    if (r >= N) return;
    int e0 = row_ptr[r], e1 = row_ptr[r + 1];

    // ---- phase A: row_sum & deg from contiguous edge_w ----
    float rs = 0.f, dg = 0.f;
    for (int e = e0 + lane; e < e1; e += 64) {
        float s = edge_w[e];
        rs += s;
        dg += (s > 0.f) ? 1.f : 0.f;
    }
#pragma unroll
    for (int off = 1; off < 64; off <<= 1) {
        rs += __shfl_xor(rs, off);
        dg += __shfl_xor(dg, off);
    }
    float invs = (rs > 0.f) ? (1.f / rs) : 1.f;
    float sw   = expf(1.f / (dg + 1.f));

    // ---- phase B: pipelined weighted gather-accumulate ----
    constexpr int F = M / 16;    // floats per lane: 8 (M=128) or 4 (M=64)
    float acc[F];
#pragma unroll
    for (int q = 0; q < F; ++q) acc[q] = 0.f;

    if (e0 < e1) {
        int  ea  = e0 + sub;
        bool v0  = ea < e1;
        int  ei0 = v0 ? ea : (e1 - 1);
        float s0 = edge_w[ei0];
        int   c0 = col[ei0];
        int  ce0 = (v0 && s0 > 0.f) ? c0 : r;
        const float4* h0p = (const float4*)(h + (size_t)ce0 * M);
        float4 ha0 = h0p[sl];
        float4 hb0;
        if constexpr (M == 128) hb0 = h0p[16 + sl];
        int  eb1 = e0 + 4 + sub;
        bool v1  = eb1 < e1;
        int  ei1 = v1 ? eb1 : (e1 - 1);
        float s1 = edge_w[ei1];
        int   c1 = col[ei1];

        for (int eb = e0; eb < e1; eb += 4) {
            int  en  = eb + 8 + sub;
            bool v2  = en < e1;
            int  ei2 = v2 ? en : (e1 - 1);
            float s2 = edge_w[ei2];
            int   c2 = col[ei2];
            int ce1 = (v1 && s1 > 0.f) ? c1 : r;
            const float4* h1p = (const float4*)(h + (size_t)ce1 * M);
            float4 ha1 = h1p[sl];
            float4 hb1;
            if constexpr (M == 128) hb1 = h1p[16 + sl];
            float w = (v0 && s0 > 0.f) ? __expf(s0 * invs) : 0.f;
            acc[0] += w * ha0.x; acc[1] += w * ha0.y;
            acc[2] += w * ha0.z; acc[3] += w * ha0.w;
            if constexpr (M == 128) {
                acc[4] += w * hb0.x; acc[5] += w * hb0.y;
                acc[6] += w * hb0.z; acc[7] += w * hb0.w;
            }
            v0 = v1; s0 = s1; ha0 = ha1;
            if constexpr (M == 128) hb0 = hb1;
            v1 = v2; s1 = s2; c1 = c2;
        }
    }
#pragma unroll
    for (int q = 0; q < F; ++q) {
        acc[q] += __shfl_xor(acc[q], 16);
        acc[q] += __shfl_xor(acc[q], 32);
    }
    const float4* hr = (const float4*)(h + (size_t)r * M);
    if constexpr (M == 128) {
        float4 a = hr[sl], b = hr[16 + sl];
        acc[0] += sw * a.x; acc[1] += sw * a.y;
        acc[2] += sw * a.z; acc[3] += sw * a.w;
        acc[4] += sw * b.x; acc[5] += sw * b.y;
        acc[6] += sw * b.z; acc[7] += sw * b.w;
    } else {
        float4 a = hr[sl];
        acc[0] += sw * a.x; acc[1] += sw * a.y;
        acc[2] += sw * a.z; acc[3] += sw * a.w;
    }
    if (RELU) {
#pragma unroll
        for (int q = 0; q < F; ++q) acc[q] = fmaxf(acc[q], 0.f);
    }
    if (sub == 0) {
        float4* o4 = (float4*)(out + (size_t)r * M);
        float4 o0 = {acc[0], acc[1], acc[2], acc[3]};
        o4[sl] = o0;
        if constexpr (M == 128) {
            float4 o1 = {acc[4], acc[5], acc[6], acc[7]};
            o4[16 + sl] = o1;
        }
    }
}

extern "C" void kernel_launch(void* const* d_in, const int* in_sizes, int n_in,
                              void* d_out, int out_size, void* d_ws,
                              size_t ws_size, hipStream_t stream) {
    const float* x  = (const float*)d_in[0];
    const int* ei   = (const int*)d_in[1];
    const float* W1 = (const float*)d_in[2];
    const float* b1 = (const float*)d_in[3];
    const float* W2 = (const float*)d_in[4];
    const float* b2 = (const float*)d_in[5];
    float* out = (float*)d_out;

    const int D = 128;
    const int N = in_sizes[0] / D;
    const int E = in_sizes[1] / 2;
    (void)out_size; (void)n_in; (void)ws_size;

    const int* row = ei;
    const int* col = ei + E;

    char* ws = (char*)d_ws;
    size_t off = 0;
    auto alloc = [&](size_t bytes) -> void* {
        void* p = ws + off;
        off = (off + bytes + 255) & ~(size_t)255;
        return p;
    };
    int*   row_ptr = (int*)  alloc((size_t)(N + 1) * sizeof(int));
    float* inv_n   = (float*)alloc((size_t)N * sizeof(float));
    float* edge_w  = (float*)alloc((size_t)E * sizeof(float));
    float* hlin    = (float*)alloc((size_t)N * 128 * sizeof(float));
    float* h1      = (float*)alloc((size_t)N * 128 * sizeof(float));

    dim3 blk(256);
    dim3 gridRows((N + 3) / 4);      // 1 wave per row, 4 waves/block
    dim3 gridNorm((N + 15) / 16);    // 4 nodes per wave
    dim3 gridE((E + 255) / 256);
    dim3 gridSim((E + 15) / 16);     // 16 edges per block (4/wave)
    dim3 gridGemm((N + 63) / 64);

    row_ptr_kernel<<<gridE, blk, 0, stream>>>(row, row_ptr, E, N);

    // ---- layer 1 ----
    inv_norm_kernel<<<gridNorm, blk, 0, stream>>>(x, inv_n, N);
    gemm_kernel<128><<<gridGemm, blk, 0, stream>>>(x, W1, b1, hlin, N);
    sim_kernel<<<gridSim, blk, 0, stream>>>(x, inv_n, row, col, edge_w, E);
    agg_kernel<128, true><<<gridRows, blk, 0, stream>>>(
        hlin, edge_w, col, row_ptr, h1, N);

    // ---- layer 2 ----
    inv_norm_kernel<<<gridNorm, blk, 0, stream>>>(h1, inv_n, N);
    gemm_kernel<64><<<gridGemm, blk, 0, stream>>>(h1, W2, b2, hlin, N);
    sim_kernel<<<gridSim, blk, 0, stream>>>(h1, inv_n, row, col, edge_w, E);
    agg_kernel<64, false><<<gridRows, blk, 0, stream>>>(
        hlin, edge_w, col, row_ptr, out, N);
}

// Round 13
// 466.205 us; speedup vs baseline: 1.0238x; 1.0238x over previous
//
#include <hip/hip_runtime.h>
#include <math.h>

// ---------------------------------------------------------------------------
// GCNGuard forward: 2x (guard-weights + linear + weighted aggregation)
// Edges sorted by (row, col) [np.unique axis=0], no self loops, unique.
// Model (r7 counters): edge kernels are bound by ~3.4 TB/s of L2-miss bytes
// on random row gathers -> minimize bytes. This round: prenormalized
// features (xn = x * invnorm) kill the inv_n[c] scalar-gather cachelines
// (~100 MB/dispatch); guard keeps the row fragment hoisted (no row
// re-gathers) and stores only edge_w (row_sum/deg recomputed in agg).
// ---------------------------------------------------------------------------

// 4 nodes per wave, 16 lanes per node: xn[node] = x[node] / ||x[node]||.
__global__ void norm_scale_kernel(const float* __restrict__ x,
                                  float* __restrict__ xn, int N) {
    int wave = (blockIdx.x * blockDim.x + threadIdx.x) >> 6;
    int lane = threadIdx.x & 63;
    int sub = lane >> 4, sl = lane & 15;
    int node = wave * 4 + sub;
    if (node >= N) return;
    const float4* xr = (const float4*)(x + (size_t)node * 128);
    float4 a = xr[sl];
    float4 b = xr[16 + sl];
    float s = a.x * a.x + a.y * a.y + a.z * a.z + a.w * a.w
            + b.x * b.x + b.y * b.y + b.z * b.z + b.w * b.w;
#pragma unroll
    for (int off = 1; off < 16; off <<= 1) s += __shfl_xor(s, off);
    float n = sqrtf(s);
    float inv = (n == 0.f) ? 1.f : 1.f / n;
    a.x *= inv; a.y *= inv; a.z *= inv; a.w *= inv;
    b.x *= inv; b.y *= inv; b.z *= inv; b.w *= inv;
    float4* o = (float4*)(xn + (size_t)node * 128);
    o[sl] = a;
    o[16 + sl] = b;
}

// Build CSR row_ptr from sorted row[] (one thread per edge, boundary fill).
__global__ void row_ptr_kernel(const int* __restrict__ row,
                               int* __restrict__ row_ptr, int E, int N) {
    int e = blockIdx.x * blockDim.x + threadIdx.x;
    if (e >= E) return;
    int r = row[e];
    if (e == 0) {
        for (int i = 0; i <= r; ++i) row_ptr[i] = 0;
    } else {
        int rp = row[e - 1];
        for (int i = rp + 1; i <= r; ++i) row_ptr[i] = e;
    }
    if (e == E - 1) {
        for (int i = r + 1; i <= N; ++i) row_ptr[i] = E;
    }
}

// One wave per row r; 4 edges in flight (16 lanes per edge); depth-1
// software pipeline on the col gathers. Inputs are prenormalized, so
// sim = dot(xn[r], xn[c]) directly. Stores thresholded sim only.
__global__ void guard_kernel(const float* __restrict__ xn,
                             const int* __restrict__ col,
                             const int* __restrict__ row_ptr,
                             float* __restrict__ edge_w, int N) {
    int r    = (blockIdx.x * blockDim.x + threadIdx.x) >> 6;
    int lane = threadIdx.x & 63;
    int sub  = lane >> 4, sl = lane & 15;
    if (r >= N) return;
    const float4* fr = (const float4*)(xn + (size_t)r * 128);
    float4 xa = fr[sl];
    float4 xb = fr[16 + sl];

    int e0 = row_ptr[r], e1 = row_ptr[r + 1];
    if (e0 >= e1) return;
    // prologue: issue block 0
    int  e  = e0 + sub;
    bool vc = e < e1;
    int  ei = vc ? e : (e1 - 1);
    int  cc = col[ei];
    const float4* fc = (const float4*)(xn + (size_t)cc * 128);
    float4 ca = fc[sl];
    float4 cb = fc[16 + sl];
    for (int eb = e0; eb < e1; eb += 4) {
        // issue next block (clamped; harmless duplicate loads past end)
        int  en  = eb + 4 + sub;
        bool vn  = en < e1;
        int  ein = vn ? en : (e1 - 1);
        int  cn  = col[ein];
        const float4* fn = (const float4*)(xn + (size_t)cn * 128);
        float4 na = fn[sl];
        float4 nb = fn[16 + sl];
        // process current block
        float p = xa.x * ca.x + xa.y * ca.y + xa.z * ca.z + xa.w * ca.w
                + xb.x * cb.x + xb.y * cb.y + xb.z * cb.z + xb.w * cb.w;
#pragma unroll
        for (int off = 1; off < 16; off <<= 1) p += __shfl_xor(p, off);
        float s = (p < 0.1f) ? 0.f : p;   // SIM_THRESH
        if (vc && sl == 0) edge_w[eb + sub] = s;
        // rotate
        vc = vn; ca = na; cb = nb;
    }
}

// Tiled fp32 GEMM: out[N x M] = A[N x 128] @ W[128 x M] + bias.
template <int M>
__launch_bounds__(256, 2)
__global__ void gemm_kernel(const float* __restrict__ A,
                            const float* __restrict__ W,
                            const float* __restrict__ bias,
                            float* __restrict__ out, int N) {
    __shared__ float Wl[128 * M];
    const int t = threadIdx.x;
    for (int i = t; i < 128 * M; i += 256) Wl[i] = W[i];
    __syncthreads();
    const int tr = t >> 4;
    const int tc = t & 15;
    const int i0 = blockIdx.x * 64 + tr * 4;
    const float4* Arow[4];
#pragma unroll
    for (int q = 0; q < 4; ++q) {
        int rq = i0 + q;
        rq = rq < N ? rq : (N - 1);
        Arow[q] = (const float4*)(A + (size_t)rq * 128);
    }
#pragma unroll
    for (int j0i = 0; j0i < M / 64; ++j0i) {
        const int j0 = j0i * 64 + tc * 4;
        float acc[4][4] = {};
        for (int k4 = 0; k4 < 32; ++k4) {
            float4 a[4], w[4];
#pragma unroll
            for (int q = 0; q < 4; ++q) a[q] = Arow[q][k4];
#pragma unroll
            for (int kk = 0; kk < 4; ++kk)
                w[kk] = *(const float4*)&Wl[(k4 * 4 + kk) * M + j0];
#pragma unroll
            for (int q = 0; q < 4; ++q) {
                const float av[4] = {a[q].x, a[q].y, a[q].z, a[q].w};
#pragma unroll
                for (int kk = 0; kk < 4; ++kk) {
                    const float wv[4] = {w[kk].x, w[kk].y, w[kk].z, w[kk].w};
#pragma unroll
                    for (int c = 0; c < 4; ++c) acc[q][c] += av[kk] * wv[c];
                }
            }
        }
        float4 bv = *(const float4*)&bias[j0];
#pragma unroll
        for (int q = 0; q < 4; ++q) {
            if (i0 + q < N) {
                float4 o;
                o.x = acc[q][0] + bv.x;
                o.y = acc[q][1] + bv.y;
                o.z = acc[q][2] + bv.z;
                o.w = acc[q][3] + bv.w;
                *(float4*)&out[(size_t)(i0 + q) * M + j0] = o;
            }
        }
    }
}

// One wave per row. Phase A: contiguous scan of edge_w[e0..e1] -> row_sum,
// deg -> invs, self_w in registers. Phase B: depth-2 pipelined
// gather-accumulate; dead edges redirect to the cache-hot self row with w=0.
template <int M, bool RELU>
__global__ void agg_kernel(const float* __restrict__ h,
                           const float* __restrict__ edge_w,
                           const int* __restrict__ col,
                           const int* __restrict__ row_ptr,
                           float* __restrict__ out, int N) {
    int r    = (blockIdx.x * blockDim.x + threadIdx.x) >> 6;
    int lane = threadIdx.x & 63;
    int sub  = lane >> 4, sl = lane & 15;
    if (r >= N) return;
    int e0 = row_ptr[r], e1 = row_ptr[r + 1];

    // ---- phase A: row_sum & deg from contiguous edge_w ----
    float rs = 0.f, dg = 0.f;
    for (int e = e0 + lane; e < e1; e += 64) {
        float s = edge_w[e];
        rs += s;
        dg += (s > 0.f) ? 1.f : 0.f;
    }
#pragma unroll
    for (int off = 1; off < 64; off <<= 1) {
        rs += __shfl_xor(rs, off);
        dg += __shfl_xor(dg, off);
    }
    float invs = (rs > 0.f) ? (1.f / rs) : 1.f;
    float sw   = expf(1.f / (dg + 1.f));

    // ---- phase B: pipelined weighted gather-accumulate ----
    constexpr int F = M / 16;    // floats per lane: 8 (M=128) or 4 (M=64)
    float acc[F];
#pragma unroll
    for (int q = 0; q < F; ++q) acc[q] = 0.f;

    if (e0 < e1) {
        int  ea  = e0 + sub;
        bool v0  = ea < e1;
        int  ei0 = v0 ? ea : (e1 - 1);
        float s0 = edge_w[ei0];
        int   c0 = col[ei0];
        int  ce0 = (v0 && s0 > 0.f) ? c0 : r;
        const float4* h0p = (const float4*)(h + (size_t)ce0 * M);
        float4 ha0 = h0p[sl];
        float4 hb0;
        if constexpr (M == 128) hb0 = h0p[16 + sl];
        int  eb1 = e0 + 4 + sub;
        bool v1  = eb1 < e1;
        int  ei1 = v1 ? eb1 : (e1 - 1);
        float s1 = edge_w[ei1];
        int   c1 = col[ei1];

        for (int eb = e0; eb < e1; eb += 4) {
            int  en  = eb + 8 + sub;
            bool v2  = en < e1;
            int  ei2 = v2 ? en : (e1 - 1);
            float s2 = edge_w[ei2];
            int   c2 = col[ei2];
            int ce1 = (v1 && s1 > 0.f) ? c1 : r;
            const float4* h1p = (const float4*)(h + (size_t)ce1 * M);
            float4 ha1 = h1p[sl];
            float4 hb1;
            if constexpr (M == 128) hb1 = h1p[16 + sl];
            float w = (v0 && s0 > 0.f) ? __expf(s0 * invs) : 0.f;
            acc[0] += w * ha0.x; acc[1] += w * ha0.y;
            acc[2] += w * ha0.z; acc[3] += w * ha0.w;
            if constexpr (M == 128) {
                acc[4] += w * hb0.x; acc[5] += w * hb0.y;
                acc[6] += w * hb0.z; acc[7] += w * hb0.w;
            }
            v0 = v1; s0 = s1; ha0 = ha1;
            if constexpr (M == 128) hb0 = hb1;
            v1 = v2; s1 = s2; c1 = c2;
        }
    }
#pragma unroll
    for (int q = 0; q < F; ++q) {
        acc[q] += __shfl_xor(acc[q], 16);
        acc[q] += __shfl_xor(acc[q], 32);
    }
    const float4* hr = (const float4*)(h + (size_t)r * M);
    if constexpr (M == 128) {
        float4 a = hr[sl], b = hr[16 + sl];
        acc[0] += sw * a.x; acc[1] += sw * a.y;
        acc[2] += sw * a.z; acc[3] += sw * a.w;
        acc[4] += sw * b.x; acc[5] += sw * b.y;
        acc[6] += sw * b.z; acc[7] += sw * b.w;
    } else {
        float4 a = hr[sl];
        acc[0] += sw * a.x; acc[1] += sw * a.y;
        acc[2] += sw * a.z; acc[3] += sw * a.w;
    }
    if (RELU) {
#pragma unroll
        for (int q = 0; q < F; ++q) acc[q] = fmaxf(acc[q], 0.f);
    }
    if (sub == 0) {
        float4* o4 = (float4*)(out + (size_t)r * M);
        float4 o0 = {acc[0], acc[1], acc[2], acc[3]};
        o4[sl] = o0;
        if constexpr (M == 128) {
            float4 o1 = {acc[4], acc[5], acc[6], acc[7]};
            o4[16 + sl] = o1;
        }
    }
}

extern "C" void kernel_launch(void* const* d_in, const int* in_sizes, int n_in,
                              void* d_out, int out_size, void* d_ws,
                              size_t ws_size, hipStream_t stream) {
    const float* x  = (const float*)d_in[0];
    const int* ei   = (const int*)d_in[1];
    const float* W1 = (const float*)d_in[2];
    const float* b1 = (const float*)d_in[3];
    const float* W2 = (const float*)d_in[4];
    const float* b2 = (const float*)d_in[5];
    float* out = (float*)d_out;

    const int D = 128;
    const int N = in_sizes[0] / D;
    const int E = in_sizes[1] / 2;
    (void)out_size; (void)n_in; (void)ws_size;

    const int* row = ei;
    const int* col = ei + E;

    char* ws = (char*)d_ws;
    size_t off = 0;
    auto alloc = [&](size_t bytes) -> void* {
        void* p = ws + off;
        off = (off + bytes + 255) & ~(size_t)255;
        return p;
    };
    int*   row_ptr = (int*)  alloc((size_t)(N + 1) * sizeof(int));
    float* edge_w  = (float*)alloc((size_t)E * sizeof(float));
    float* bufA    = (float*)alloc((size_t)N * 128 * sizeof(float)); // xn / hlin / h2lin
    float* bufB    = (float*)alloc((size_t)N * 128 * sizeof(float)); // h1

    dim3 blk(256);
    dim3 gridRows((N + 3) / 4);      // 1 wave per row, 4 waves/block
    dim3 gridNorm((N + 15) / 16);    // 4 nodes per wave
    dim3 gridE((E + 255) / 256);
    dim3 gridGemm((N + 63) / 64);

    row_ptr_kernel<<<gridE, blk, 0, stream>>>(row, row_ptr, E, N);

    // ---- layer 1 ----  (bufA: xn(x) -> consumed by guard -> reused as hlin)
    norm_scale_kernel<<<gridNorm, blk, 0, stream>>>(x, bufA, N);
    guard_kernel<<<gridRows, blk, 0, stream>>>(bufA, col, row_ptr, edge_w, N);
    gemm_kernel<128><<<gridGemm, blk, 0, stream>>>(x, W1, b1, bufA, N);
    agg_kernel<128, true><<<gridRows, blk, 0, stream>>>(
        bufA, edge_w, col, row_ptr, bufB, N);

    // ---- layer 2 ----  (bufA: xn(h1) -> consumed by guard -> reused as h2lin)
    norm_scale_kernel<<<gridNorm, blk, 0, stream>>>(bufB, bufA, N);
    guard_kernel<<<gridRows, blk, 0, stream>>>(bufA, col, row_ptr, edge_w, N);
    gemm_kernel<64><<<gridGemm, blk, 0, stream>>>(bufB, W2, b2, bufA, N);
    agg_kernel<64, false><<<gridRows, blk, 0, stream>>>(
        bufA, edge_w, col, row_ptr, out, N);
}